// Round 5
// baseline (244.562 us; speedup 1.0000x reference)
//
#include <hip/hip_runtime.h>

#define BB 8
#define LL 200
#define HH 128
#define NHEAD 4
#define HDIM 32
#define NBLK 2
#define BL (BB * LL)
#define NT 257            // TIME_SPAN+1
#define QT 8              // attn queries per tile
#define NQT 25            // 200/8
#define SSP 208           // attn score row stride
#define KTP 66            // attn KstT row stride
#define TSP 132           // GEMM tile row stride [r][k]

static constexpr float SQRT_H    = 11.313708498984761f;   // sqrt(128)
static constexpr float INV_SCALE = 0.17677669529663687f;  // 1/sqrt(32)
static constexpr float PADV      = -4294967295.0f;        // -2^32+1

// ===== QKV GEMM v2: 300 blocks, each = (mt, group of 4 col-tiles) =========
__global__ void k_qkv_gemm(const float* __restrict__ seqs_in,
                           const int* __restrict__ log_seqs,
                           const float* __restrict__ item_emb,
                           const float* __restrict__ g, const float* __restrict__ bia,
                           const float* __restrict__ Wq, const float* __restrict__ bq,
                           const float* __restrict__ Wk, const float* __restrict__ bk,
                           const float* __restrict__ Wv, const float* __restrict__ bv,
                           const float* __restrict__ posK, const float* __restrict__ posV,
                           float* __restrict__ Qin, float* __restrict__ Q,
                           float* __restrict__ K, float* __restrict__ V) {
    int mt = blockIdx.x / 6, ntg = blockIdx.x % 6;
    int nt0 = ntg * 4;                 // 4 consecutive nt tiles, same matsel
    int matsel = nt0 >> 3;             // 0=Q 1=K 2=V
    int jb0 = (nt0 & 7) * 16;
    int row0 = mt * 32;
    int tid = threadIdx.x;
    __shared__ float As[32 * TSP];     // 16.9 KB [m][k]
    __shared__ float Bs[2][16 * TSP];  // 2 x 8.4 KB [j][k]

    {   // stage A: 32 rows x 128, 8 threads/row; LN for Q-groups (once)
        int r = tid >> 3, seg = tid & 7;
        int row = row0 + r;
        float4 vv[4];
        if (seqs_in) {
            #pragma unroll
            for (int i = 0; i < 4; i++)
                vv[i] = *(const float4*)(seqs_in + (size_t)row * HH + seg * 16 + i * 4);
        } else {
            int idx = log_seqs[row];
            if (idx == 0) {
                #pragma unroll
                for (int i = 0; i < 4; i++) vv[i] = make_float4(0.f, 0.f, 0.f, 0.f);
            } else {
                #pragma unroll
                for (int i = 0; i < 4; i++) {
                    float4 e = *(const float4*)(item_emb + (size_t)idx * HH + seg * 16 + i * 4);
                    vv[i] = make_float4(e.x * SQRT_H, e.y * SQRT_H, e.z * SQRT_H, e.w * SQRT_H);
                }
            }
        }
        if (matsel == 0) {
            float s = 0.f, s2 = 0.f;
            #pragma unroll
            for (int i = 0; i < 4; i++) {
                s  += vv[i].x + vv[i].y + vv[i].z + vv[i].w;
                s2 += vv[i].x * vv[i].x + vv[i].y * vv[i].y + vv[i].z * vv[i].z + vv[i].w * vv[i].w;
            }
            #pragma unroll
            for (int off = 1; off < 8; off <<= 1) {
                s  += __shfl_xor(s, off);
                s2 += __shfl_xor(s2, off);
            }
            float mean = s * (1.f / HH);
            float var  = s2 * (1.f / HH) - mean * mean;
            float inv  = 1.f / sqrtf(var + 1e-8f);
            #pragma unroll
            for (int i = 0; i < 4; i++) {
                int k = seg * 16 + i * 4;
                float4 g4 = *(const float4*)(g + k);
                float4 b4 = *(const float4*)(bia + k);
                float4 y;
                y.x = (vv[i].x - mean) * inv * g4.x + b4.x;
                y.y = (vv[i].y - mean) * inv * g4.y + b4.y;
                y.z = (vv[i].z - mean) * inv * g4.z + b4.z;
                y.w = (vv[i].w - mean) * inv * g4.w + b4.w;
                *(float4*)&As[r * TSP + k] = y;
                if (nt0 == 0) *(float4*)(Qin + (size_t)row * HH + k) = y;
            }
        } else {
            #pragma unroll
            for (int i = 0; i < 4; i++)
                *(float4*)&As[r * TSP + seg * 16 + i * 4] = vv[i];
        }
    }
    const float* W = (matsel == 0) ? Wq : (matsel == 1) ? Wk : Wv;
    int j = tid >> 4, seg16 = tid & 15;
    float4 w0 = *(const float4*)(W + (size_t)(jb0 + j) * HH + seg16 * 8);
    float4 w1 = *(const float4*)(W + (size_t)(jb0 + j) * HH + seg16 * 8 + 4);
    *(float4*)&Bs[0][j * TSP + seg16 * 8]     = w0;
    *(float4*)&Bs[0][j * TSP + seg16 * 8 + 4] = w1;
    __syncthreads();

    int m = tid >> 3, jg = tid & 7;    // 2 output cols per thread
    const float* ar = &As[m * TSP];
    #pragma unroll
    for (int it = 0; it < 4; it++) {
        int jb = jb0 + it * 16;
        if (it < 3) {   // issue next tile's loads BEFORE the dot
            int jbn = jb0 + (it + 1) * 16;
            w0 = *(const float4*)(W + (size_t)(jbn + j) * HH + seg16 * 8);
            w1 = *(const float4*)(W + (size_t)(jbn + j) * HH + seg16 * 8 + 4);
        }
        float acc0 = 0.f, acc1 = 0.f;
        const float* b0r = &Bs[it & 1][(jg * 2) * TSP];
        const float* b1r = &Bs[it & 1][(jg * 2 + 1) * TSP];
        #pragma unroll 4
        for (int k4 = 0; k4 < 32; k4++) {
            float4 a  = *(const float4*)(ar + k4 * 4);
            float4 b0 = *(const float4*)(b0r + k4 * 4);
            float4 b1 = *(const float4*)(b1r + k4 * 4);
            acc0 += a.x * b0.x + a.y * b0.y + a.z * b0.z + a.w * b0.w;
            acc1 += a.x * b1.x + a.y * b1.y + a.z * b1.z + a.w * b1.w;
        }
        int row = row0 + m;
        int col = jb + jg * 2;
        int l = row % LL;
        if (matsel == 0) {
            float2 bb = *(const float2*)(bq + col);
            *(float2*)(Q + (size_t)row * HH + col) =
                make_float2((acc0 + bb.x) * INV_SCALE, (acc1 + bb.y) * INV_SCALE);
        } else if (matsel == 1) {
            float2 bb = *(const float2*)(bk + col);
            float2 pk = *(const float2*)(posK + (size_t)l * HH + col);
            *(float2*)(K + (size_t)row * HH + col) =
                make_float2(acc0 + bb.x + pk.x, acc1 + bb.y + pk.y);
        } else {
            float2 bb = *(const float2*)(bv + col);
            float2 pv = *(const float2*)(posV + (size_t)l * HH + col);
            *(float2*)(V + (size_t)row * HH + col) =
                make_float2(acc0 + bb.x + pv.x, acc1 + bb.y + pv.y);
        }
        if (it < 3) {   // write-late: vmcnt wait lands here, after the dot
            *(float4*)&Bs[(it + 1) & 1][j * TSP + seg16 * 8]     = w0;
            *(float4*)&Bs[(it + 1) & 1][j * TSP + seg16 * 8 + 4] = w1;
        }
        __syncthreads();
    }
}

// ===== attention v4 (unchanged from R4) ====================================
__global__ void k_attn(const float* __restrict__ Q, const float* __restrict__ K,
                       const float* __restrict__ V,
                       const float* __restrict__ timeK, const float* __restrict__ timeV,
                       const int* __restrict__ tm,
                       float* __restrict__ att) {
    int bn = blockIdx.x & 31;
    int b = bn >> 2, n = bn & 3;
    int qt = (NQT - 1) - (blockIdx.x >> 5);
    int q0 = qt * QT;
    int kmax = q0 + QT - 1;
    int tid = threadIdx.x;
    int wv = tid >> 6, ln = tid & 63;

    __shared__ float KstT[2][HDIM * KTP];  // 2 x 8.4 KB staging (dbuf)
    __shared__ float DTW[QT * NT];         // 8.2 KB DT table
    __shared__ float Ssc[QT * SSP];        // 6.7 KB scores -> P
    __shared__ float Ost[QT * HDIM];       // 1.0 KB
    __shared__ int   tmst[QT * LL];        // 6.4 KB

    Ost[tid] = 0.f;
    #pragma unroll
    for (int qi = 0; qi < QT; qi++)
        if (tid < LL)
            tmst[qi * LL + tid] = tm[((size_t)(b * LL + q0 + qi)) * LL + tid];

    int k2 = tid & 31, qi_c = tid >> 5;
    int q = q0 + qi_c;

    float qreg[HDIM];
    {
        const float* qp = Q + ((size_t)(b * LL + q)) * HH + n * HDIM;
        #pragma unroll
        for (int i = 0; i < 8; i++) {
            float4 v = *(const float4*)(qp + i * 4);
            qreg[i * 4 + 0] = v.x; qreg[i * 4 + 1] = v.y;
            qreg[i * 4 + 2] = v.z; qreg[i * 4 + 3] = v.w;
        }
    }

    const int nchS = (kmax >> 6) + 1;      // K chunks (1..4)
    const int ncht = 5 + nchS;             // total chunks

    int rS = tid >> 3, d4 = tid & 7;       // staging coords: rows rS, rS+32

    auto ld_chunk = [&](int c, float4& f0, float4& f1) {
        f0 = make_float4(0.f, 0.f, 0.f, 0.f);
        f1 = make_float4(0.f, 0.f, 0.f, 0.f);
        if (c < 5) {
            int tau = c * 64 + rS;
            if (tau < NT)      f0 = *(const float4*)(timeK + (size_t)tau * HH + n * HDIM + d4 * 4);
            if (tau + 32 < NT) f1 = *(const float4*)(timeK + (size_t)(tau + 32) * HH + n * HDIM + d4 * 4);
        } else {
            int k = (c - 5) * 64 + rS;
            if (k < LL)      f0 = *(const float4*)(K + ((size_t)(b * LL + k)) * HH + n * HDIM + d4 * 4);
            if (k + 32 < LL) f1 = *(const float4*)(K + ((size_t)(b * LL + k + 32)) * HH + n * HDIM + d4 * 4);
        }
    };
    auto wr_chunk = [&](float4 f0, float4 f1, float* buf) {
        buf[(d4 * 4 + 0) * KTP + rS] = f0.x;
        buf[(d4 * 4 + 1) * KTP + rS] = f0.y;
        buf[(d4 * 4 + 2) * KTP + rS] = f0.z;
        buf[(d4 * 4 + 3) * KTP + rS] = f0.w;
        buf[(d4 * 4 + 0) * KTP + rS + 32] = f1.x;
        buf[(d4 * 4 + 1) * KTP + rS + 32] = f1.y;
        buf[(d4 * 4 + 2) * KTP + rS + 32] = f1.z;
        buf[(d4 * 4 + 3) * KTP + rS + 32] = f1.w;
    };

    {
        float4 c0, c1;
        ld_chunk(0, c0, c1);
        wr_chunk(c0, c1, KstT[0]);
    }
    __syncthreads();
    for (int c = 0; c < ncht; c++) {
        float4 n0, n1;
        bool more = (c + 1 < ncht);
        if (more) ld_chunk(c + 1, n0, n1);   // issue-early
        const float* buf = KstT[c & 1];
        float a0 = 0.f, a1 = 0.f;
        #pragma unroll 4
        for (int d = 0; d < HDIM; d++) {
            float qv = qreg[d];
            float2 kv = *(const float2*)&buf[d * KTP + k2 * 2];
            a0 += qv * kv.x; a1 += qv * kv.y;
        }
        if (c < 5) {
            int tau0 = c * 64 + k2 * 2;
            if (tau0 < NT)     DTW[qi_c * NT + tau0]     = a0;
            if (tau0 + 1 < NT) DTW[qi_c * NT + tau0 + 1] = a1;
        } else {
            int k0 = (c - 5) * 64 + k2 * 2;
            if (k0 <= kmax)     Ssc[qi_c * SSP + k0]     = a0;   // raw QK; DT added in softmax
            if (k0 + 1 <= kmax) Ssc[qi_c * SSP + k0 + 1] = a1;
        }
        if (more) wr_chunk(n0, n1, KstT[(c + 1) & 1]);   // write-late
        __syncthreads();
    }

    // softmax with fused DT gather (LDS): sv = QK + DT[tm[k]]
    for (int rr = 0; rr < 2; rr++) {
        int qi = wv + rr * 4;
        int qq = q0 + qi;
        float sv[4];
        float m = PADV;
        #pragma unroll
        for (int jj = 0; jj < 4; jj++) {
            int k = ln + 64 * jj;
            sv[jj] = (k <= qq) ? (Ssc[qi * SSP + k] + DTW[qi * NT + tmst[qi * LL + k]]) : PADV;
            m = fmaxf(m, sv[jj]);
        }
        for (int off = 32; off; off >>= 1) m = fmaxf(m, __shfl_xor(m, off));
        float sum = 0.f;
        #pragma unroll
        for (int jj = 0; jj < 4; jj++) {
            int k = ln + 64 * jj;
            sv[jj] = (k <= qq) ? __expf(sv[jj] - m) : 0.f;
            sum += sv[jj];
        }
        for (int off = 32; off; off >>= 1) sum += __shfl_xor(sum, off);
        float inv = 1.f / sum;
        #pragma unroll
        for (int jj = 0; jj < 4; jj++) {
            int k = ln + 64 * jj;
            if (k < SSP) Ssc[qi * SSP + k] = (k <= qq) ? sv[jj] * inv : 0.f;
        }
    }
    __syncthreads();

    // O = P@(Vh + timeVh[tm])
    int d = tid & 31, kg = tid >> 5;
    float acc[QT] = {0,0,0,0,0,0,0,0};
    const float* vb  = V + ((size_t)(b * LL)) * HH + n * HDIM + d;
    const float* tvb = timeV + n * HDIM + d;
    for (int k = kg; k <= kmax; k += 8) {
        float v = vb[(size_t)k * HH];
        #pragma unroll
        for (int qi = 0; qi < QT; qi++) {
            float p  = Ssc[qi * SSP + k];
            float tv = tvb[(size_t)tmst[qi * LL + k] * HH];
            acc[qi] += p * (v + tv);
        }
    }
    #pragma unroll
    for (int qi = 0; qi < QT; qi++) atomicAdd(&Ost[qi * HDIM + d], acc[qi]);
    __syncthreads();
    {
        int qi = tid >> 5;
        att[((size_t)(b * LL + q0 + qi)) * HH + n * HDIM + (tid & 31)] = Ost[tid];
    }
}

// ===== fused FF (ff1+ff2): 100 blocks x 16 full rows =======================
// As = LN(Qin+att) staged once; h1 kept in LDS (no global round-trip);
// ff2's residual LN term IS As (same g,b) — no recompute. Optionally
// (LAST=1) appends last-LN + pos/neg logits, skipping the seqs write.
template <int LAST>
__device__ __forceinline__ void ff_body(
        const float* __restrict__ Qin, const float* __restrict__ att,
        const float* __restrict__ g, const float* __restrict__ bia,
        const float* __restrict__ W1, const float* __restrict__ b1,
        const float* __restrict__ W2, const float* __restrict__ b2,
        const int* __restrict__ log_seqs, float* __restrict__ out,
        const float* __restrict__ last_g, const float* __restrict__ last_b,
        const float* __restrict__ item_emb,
        const int* __restrict__ pos, const int* __restrict__ neg,
        float* __restrict__ logits) {
    int row0 = blockIdx.x * 16;
    int tid = threadIdx.x;
    __shared__ float As[16 * TSP];      // LN(Qin+att), later final rows
    __shared__ float Hs[16 * TSP];      // h1
    __shared__ float Bs[2][16 * TSP];   // W chunk dbuf

    {   // stage A = LN(Qin+att), 16 threads/row
        int r = tid >> 4, seg = tid & 15;
        int row = row0 + r;
        float4 vv[2];
        #pragma unroll
        for (int i = 0; i < 2; i++) {
            int k = seg * 8 + i * 4;
            float4 q4 = *(const float4*)(Qin + (size_t)row * HH + k);
            float4 a4 = *(const float4*)(att + (size_t)row * HH + k);
            vv[i] = make_float4(q4.x + a4.x, q4.y + a4.y, q4.z + a4.z, q4.w + a4.w);
        }
        float s = 0.f, s2 = 0.f;
        #pragma unroll
        for (int i = 0; i < 2; i++) {
            s  += vv[i].x + vv[i].y + vv[i].z + vv[i].w;
            s2 += vv[i].x * vv[i].x + vv[i].y * vv[i].y + vv[i].z * vv[i].z + vv[i].w * vv[i].w;
        }
        #pragma unroll
        for (int off = 1; off < 16; off <<= 1) {
            s  += __shfl_xor(s, off);
            s2 += __shfl_xor(s2, off);
        }
        float mean = s * (1.f / HH);
        float var  = s2 * (1.f / HH) - mean * mean;
        float inv  = 1.f / sqrtf(var + 1e-8f);
        #pragma unroll
        for (int i = 0; i < 2; i++) {
            int k = seg * 8 + i * 4;
            float4 g4 = *(const float4*)(g + k);
            float4 b4 = *(const float4*)(bia + k);
            float4 y;
            y.x = (vv[i].x - mean) * inv * g4.x + b4.x;
            y.y = (vv[i].y - mean) * inv * g4.y + b4.y;
            y.z = (vv[i].z - mean) * inv * g4.z + b4.z;
            y.w = (vv[i].w - mean) * inv * g4.w + b4.w;
            *(float4*)&As[r * TSP + k] = y;
        }
    }
    int j = tid >> 4, seg16 = tid & 15;
    float4 w0 = *(const float4*)(W1 + (size_t)j * HH + seg16 * 8);
    float4 w1 = *(const float4*)(W1 + (size_t)j * HH + seg16 * 8 + 4);
    *(float4*)&Bs[0][j * TSP + seg16 * 8]     = w0;
    *(float4*)&Bs[0][j * TSP + seg16 * 8 + 4] = w1;
    __syncthreads();

    int m = tid >> 4, jj = tid & 15;
    const float* ar = &As[m * TSP];
    // phase 1: h1 = relu(As@W1^T + b1), 8 chunks of 16 cols, dbuf prefetch
    #pragma unroll
    for (int it = 0; it < 8; it++) {
        {   // prefetch next chunk (W1 it+1, or W2 chunk 0 at the end)
            const float* Wn = (it < 7) ? W1 : W2;
            int jbn = (it < 7) ? (it + 1) * 16 : 0;
            w0 = *(const float4*)(Wn + (size_t)(jbn + j) * HH + seg16 * 8);
            w1 = *(const float4*)(Wn + (size_t)(jbn + j) * HH + seg16 * 8 + 4);
        }
        float acc = 0.f;
        const float* br = &Bs[it & 1][jj * TSP];
        #pragma unroll 4
        for (int k4 = 0; k4 < 32; k4++) {
            float4 a = *(const float4*)(ar + k4 * 4);
            float4 b = *(const float4*)(br + k4 * 4);
            acc += a.x * b.x + a.y * b.y + a.z * b.z + a.w * b.w;
        }
        int col = it * 16 + jj;
        float t = acc + b1[col];
        Hs[m * TSP + col] = t > 0.f ? t : 0.f;
        *(float4*)&Bs[(it + 1) & 1][j * TSP + seg16 * 8]     = w0;
        *(float4*)&Bs[(it + 1) & 1][j * TSP + seg16 * 8 + 4] = w1;
        __syncthreads();
    }
    // phase 2: o = Hs@W2^T + b2 + As, masked
    const float* hr = &Hs[m * TSP];
    int row = row0 + m;
    int dead = (log_seqs[row] == 0);
    #pragma unroll
    for (int it = 0; it < 8; it++) {
        if (it < 7) {
            int jbn = (it + 1) * 16;
            w0 = *(const float4*)(W2 + (size_t)(jbn + j) * HH + seg16 * 8);
            w1 = *(const float4*)(W2 + (size_t)(jbn + j) * HH + seg16 * 8 + 4);
        }
        float acc = 0.f;
        const float* br = &Bs[it & 1][jj * TSP];
        #pragma unroll 4
        for (int k4 = 0; k4 < 32; k4++) {
            float4 a = *(const float4*)(hr + k4 * 4);
            float4 b = *(const float4*)(br + k4 * 4);
            acc += a.x * b.x + a.y * b.y + a.z * b.z + a.w * b.w;
        }
        int col = it * 16 + jj;
        float o = acc + b2[col] + As[m * TSP + col];
        if (dead) o = 0.f;
        if (LAST) {
            As[m * TSP + col] = o;     // keep final row in LDS for ln+logits
        } else {
            out[(size_t)row * HH + col] = o;
        }
        if (it < 7) {
            *(float4*)&Bs[(it + 1) & 1][j * TSP + seg16 * 8]     = w0;
            *(float4*)&Bs[(it + 1) & 1][j * TSP + seg16 * 8 + 4] = w1;
        }
        __syncthreads();
    }
    if (LAST) {
        // last-LN + pos/neg logits on the 16 in-LDS rows, 16 threads/row
        int r = tid >> 4, seg = tid & 15;
        int lrow = row0 + r;
        float4 v0 = *(float4*)&As[r * TSP + seg * 8];
        float4 v1 = *(float4*)&As[r * TSP + seg * 8 + 4];
        float s  = v0.x + v0.y + v0.z + v0.w + v1.x + v1.y + v1.z + v1.w;
        float s2 = v0.x * v0.x + v0.y * v0.y + v0.z * v0.z + v0.w * v0.w
                 + v1.x * v1.x + v1.y * v1.y + v1.z * v1.z + v1.w * v1.w;
        #pragma unroll
        for (int off = 1; off < 16; off <<= 1) {
            s  += __shfl_xor(s, off);
            s2 += __shfl_xor(s2, off);
        }
        float mean = s * (1.f / HH);
        float var  = s2 * (1.f / HH) - mean * mean;
        float inv  = 1.f / sqrtf(var + 1e-8f);
        int ip = pos[lrow], in_ = neg[lrow];
        const float* pe = item_emb + (size_t)ip * HH + seg * 8;
        const float* ne = item_emb + (size_t)in_ * HH + seg * 8;
        float4 lg0 = *(const float4*)(last_g + seg * 8);
        float4 lg1 = *(const float4*)(last_g + seg * 8 + 4);
        float4 lb0 = *(const float4*)(last_b + seg * 8);
        float4 lb1 = *(const float4*)(last_b + seg * 8 + 4);
        float4 p0 = *(const float4*)(pe),  p1 = *(const float4*)(pe + 4);
        float4 n0 = *(const float4*)(ne),  n1 = *(const float4*)(ne + 4);
        float f0 = (v0.x - mean) * inv * lg0.x + lb0.x;
        float f1 = (v0.y - mean) * inv * lg0.y + lb0.y;
        float f2 = (v0.z - mean) * inv * lg0.z + lb0.z;
        float f3 = (v0.w - mean) * inv * lg0.w + lb0.w;
        float f4 = (v1.x - mean) * inv * lg1.x + lb1.x;
        float f5 = (v1.y - mean) * inv * lg1.y + lb1.y;
        float f6 = (v1.z - mean) * inv * lg1.z + lb1.z;
        float f7 = (v1.w - mean) * inv * lg1.w + lb1.w;
        float vp = f0 * p0.x + f1 * p0.y + f2 * p0.z + f3 * p0.w
                 + f4 * p1.x + f5 * p1.y + f6 * p1.z + f7 * p1.w;
        float vn = f0 * n0.x + f1 * n0.y + f2 * n0.z + f3 * n0.w
                 + f4 * n1.x + f5 * n1.y + f6 * n1.z + f7 * n1.w;
        #pragma unroll
        for (int off = 1; off < 16; off <<= 1) {
            vp += __shfl_xor(vp, off);
            vn += __shfl_xor(vn, off);
        }
        if (seg == 0) {
            logits[lrow]      = vp;
            logits[BL + lrow] = vn;
        }
    }
}

__global__ void k_ff(const float* __restrict__ Qin, const float* __restrict__ att,
                     const float* __restrict__ g, const float* __restrict__ bia,
                     const float* __restrict__ W1, const float* __restrict__ b1,
                     const float* __restrict__ W2, const float* __restrict__ b2,
                     const int* __restrict__ log_seqs, float* __restrict__ out) {
    ff_body<0>(Qin, att, g, bia, W1, b1, W2, b2, log_seqs, out,
               nullptr, nullptr, nullptr, nullptr, nullptr, nullptr);
}

__global__ void k_fflast(const float* __restrict__ Qin, const float* __restrict__ att,
                         const float* __restrict__ g, const float* __restrict__ bia,
                         const float* __restrict__ W1, const float* __restrict__ b1,
                         const float* __restrict__ W2, const float* __restrict__ b2,
                         const int* __restrict__ log_seqs,
                         const float* __restrict__ last_g, const float* __restrict__ last_b,
                         const float* __restrict__ item_emb,
                         const int* __restrict__ pos, const int* __restrict__ neg,
                         float* __restrict__ logits) {
    ff_body<1>(Qin, att, g, bia, W1, b1, W2, b2, log_seqs, nullptr,
               last_g, last_b, item_emb, pos, neg, logits);
}

extern "C" void kernel_launch(void* const* d_in, const int* in_sizes, int n_in,
                              void* d_out, int out_size, void* d_ws, size_t ws_size,
                              hipStream_t stream) {
    const int* log_seqs   = (const int*)d_in[1];
    const int* tm         = (const int*)d_in[2];
    const int* pos_seqs   = (const int*)d_in[3];
    const int* neg_seqs   = (const int*)d_in[4];
    const float* item_emb = (const float*)d_in[5];
    const float* posK     = (const float*)d_in[6];
    const float* posV     = (const float*)d_in[7];
    const float* timeK    = (const float*)d_in[8];
    const float* timeV    = (const float*)d_in[9];
    const float* attn_g   = (const float*)d_in[10];
    const float* attn_b   = (const float*)d_in[11];
    const float* Wq       = (const float*)d_in[12];
    const float* bq       = (const float*)d_in[13];
    const float* Wk       = (const float*)d_in[14];
    const float* bk       = (const float*)d_in[15];
    const float* Wv       = (const float*)d_in[16];
    const float* bv       = (const float*)d_in[17];
    const float* fwd_g    = (const float*)d_in[18];
    const float* fwd_b    = (const float*)d_in[19];
    const float* W1       = (const float*)d_in[20];
    const float* b1       = (const float*)d_in[21];
    const float* W2       = (const float*)d_in[22];
    const float* b2       = (const float*)d_in[23];
    const float* last_g   = (const float*)d_in[24];
    const float* last_b   = (const float*)d_in[25];

    float* seqs = (float*)d_ws;            // 6 x B*L*H f32
    float* Qin  = seqs + (size_t)BL * HH;
    float* Qb   = Qin  + (size_t)BL * HH;
    float* Kb   = Qb   + (size_t)BL * HH;
    float* Vb   = Kb   + (size_t)BL * HH;
    float* att  = Vb   + (size_t)BL * HH;

    for (int i = 0; i < NBLK; i++) {
        k_qkv_gemm<<<300, 256, 0, stream>>>(i == 0 ? nullptr : seqs, log_seqs, item_emb,
                                            attn_g + i * HH, attn_b + i * HH,
                                            Wq + (size_t)i * HH * HH, bq + i * HH,
                                            Wk + (size_t)i * HH * HH, bk + i * HH,
                                            Wv + (size_t)i * HH * HH, bv + i * HH,
                                            posK, posV, Qin, Qb, Kb, Vb);
        k_attn<<<NQT * 32, 256, 0, stream>>>(Qb, Kb, Vb, timeK, timeV, tm, att);
        if (i < NBLK - 1) {
            k_ff<<<100, 256, 0, stream>>>(Qin, att, fwd_g + i * HH, fwd_b + i * HH,
                                          W1 + (size_t)i * HH * HH, b1 + i * HH,
                                          W2 + (size_t)i * HH * HH, b2 + i * HH,
                                          log_seqs, seqs);
        } else {
            k_fflast<<<100, 256, 0, stream>>>(Qin, att, fwd_g + i * HH, fwd_b + i * HH,
                                              W1 + (size_t)i * HH * HH, b1 + i * HH,
                                              W2 + (size_t)i * HH * HH, b2 + i * HH,
                                              log_seqs, last_g, last_b, item_emb,
                                              pos_seqs, neg_seqs, (float*)d_out);
        }
    }
}

// Round 6
// 238.409 us; speedup vs baseline: 1.0258x; 1.0258x over previous
//
#include <hip/hip_runtime.h>

#define BB 8
#define LL 200
#define HH 128
#define NHEAD 4
#define HDIM 32
#define NBLK 2
#define BL (BB * LL)
#define NT 257            // TIME_SPAN+1
#define NTP 264           // DTW row stride (bank-spread)
#define QT 8              // attn queries per tile
#define NQT 25            // 200/8
#define SSP 208           // attn score row stride
#define TSP 132           // GEMM tile row stride [r][k]

static constexpr float SQRT_H    = 11.313708498984761f;   // sqrt(128)
static constexpr float INV_SCALE = 0.17677669529663687f;  // 1/sqrt(32)
static constexpr float PADV      = -4294967295.0f;        // -2^32+1

// ===== QKV GEMM v2 (R4-verified): 300 blocks x 4 col-tiles ================
__global__ void k_qkv_gemm(const float* __restrict__ seqs_in,
                           const int* __restrict__ log_seqs,
                           const float* __restrict__ item_emb,
                           const float* __restrict__ g, const float* __restrict__ bia,
                           const float* __restrict__ Wq, const float* __restrict__ bq,
                           const float* __restrict__ Wk, const float* __restrict__ bk,
                           const float* __restrict__ Wv, const float* __restrict__ bv,
                           const float* __restrict__ posK, const float* __restrict__ posV,
                           float* __restrict__ Qin, float* __restrict__ Q,
                           float* __restrict__ K, float* __restrict__ V) {
    int mt = blockIdx.x / 6, ntg = blockIdx.x % 6;
    int nt0 = ntg * 4;                 // 4 consecutive nt tiles, same matsel
    int matsel = nt0 >> 3;             // 0=Q 1=K 2=V
    int jb0 = (nt0 & 7) * 16;
    int row0 = mt * 32;
    int tid = threadIdx.x;
    __shared__ float As[32 * TSP];     // 16.9 KB [m][k]
    __shared__ float Bs[2][16 * TSP];  // 2 x 8.4 KB [j][k]

    {   // stage A: 32 rows x 128, 8 threads/row; LN for Q-groups (once)
        int r = tid >> 3, seg = tid & 7;
        int row = row0 + r;
        float4 vv[4];
        if (seqs_in) {
            #pragma unroll
            for (int i = 0; i < 4; i++)
                vv[i] = *(const float4*)(seqs_in + (size_t)row * HH + seg * 16 + i * 4);
        } else {
            int idx = log_seqs[row];
            if (idx == 0) {
                #pragma unroll
                for (int i = 0; i < 4; i++) vv[i] = make_float4(0.f, 0.f, 0.f, 0.f);
            } else {
                #pragma unroll
                for (int i = 0; i < 4; i++) {
                    float4 e = *(const float4*)(item_emb + (size_t)idx * HH + seg * 16 + i * 4);
                    vv[i] = make_float4(e.x * SQRT_H, e.y * SQRT_H, e.z * SQRT_H, e.w * SQRT_H);
                }
            }
        }
        if (matsel == 0) {
            float s = 0.f, s2 = 0.f;
            #pragma unroll
            for (int i = 0; i < 4; i++) {
                s  += vv[i].x + vv[i].y + vv[i].z + vv[i].w;
                s2 += vv[i].x * vv[i].x + vv[i].y * vv[i].y + vv[i].z * vv[i].z + vv[i].w * vv[i].w;
            }
            #pragma unroll
            for (int off = 1; off < 8; off <<= 1) {
                s  += __shfl_xor(s, off);
                s2 += __shfl_xor(s2, off);
            }
            float mean = s * (1.f / HH);
            float var  = s2 * (1.f / HH) - mean * mean;
            float inv  = 1.f / sqrtf(var + 1e-8f);
            #pragma unroll
            for (int i = 0; i < 4; i++) {
                int k = seg * 16 + i * 4;
                float4 g4 = *(const float4*)(g + k);
                float4 b4 = *(const float4*)(bia + k);
                float4 y;
                y.x = (vv[i].x - mean) * inv * g4.x + b4.x;
                y.y = (vv[i].y - mean) * inv * g4.y + b4.y;
                y.z = (vv[i].z - mean) * inv * g4.z + b4.z;
                y.w = (vv[i].w - mean) * inv * g4.w + b4.w;
                *(float4*)&As[r * TSP + k] = y;
                if (nt0 == 0) *(float4*)(Qin + (size_t)row * HH + k) = y;
            }
        } else {
            #pragma unroll
            for (int i = 0; i < 4; i++)
                *(float4*)&As[r * TSP + seg * 16 + i * 4] = vv[i];
        }
    }
    const float* W = (matsel == 0) ? Wq : (matsel == 1) ? Wk : Wv;
    int j = tid >> 4, seg16 = tid & 15;
    float4 w0 = *(const float4*)(W + (size_t)(jb0 + j) * HH + seg16 * 8);
    float4 w1 = *(const float4*)(W + (size_t)(jb0 + j) * HH + seg16 * 8 + 4);
    *(float4*)&Bs[0][j * TSP + seg16 * 8]     = w0;
    *(float4*)&Bs[0][j * TSP + seg16 * 8 + 4] = w1;
    __syncthreads();

    int m = tid >> 3, jg = tid & 7;    // 2 output cols per thread
    const float* ar = &As[m * TSP];
    #pragma unroll
    for (int it = 0; it < 4; it++) {
        int jb = jb0 + it * 16;
        if (it < 3) {   // issue next tile's loads BEFORE the dot
            int jbn = jb0 + (it + 1) * 16;
            w0 = *(const float4*)(W + (size_t)(jbn + j) * HH + seg16 * 8);
            w1 = *(const float4*)(W + (size_t)(jbn + j) * HH + seg16 * 8 + 4);
        }
        float acc0 = 0.f, acc1 = 0.f;
        const float* b0r = &Bs[it & 1][(jg * 2) * TSP];
        const float* b1r = &Bs[it & 1][(jg * 2 + 1) * TSP];
        #pragma unroll 4
        for (int k4 = 0; k4 < 32; k4++) {
            float4 a  = *(const float4*)(ar + k4 * 4);
            float4 b0 = *(const float4*)(b0r + k4 * 4);
            float4 b1 = *(const float4*)(b1r + k4 * 4);
            acc0 += a.x * b0.x + a.y * b0.y + a.z * b0.z + a.w * b0.w;
            acc1 += a.x * b1.x + a.y * b1.y + a.z * b1.z + a.w * b1.w;
        }
        int row = row0 + m;
        int col = jb + jg * 2;
        int l = row % LL;
        if (matsel == 0) {
            float2 bb = *(const float2*)(bq + col);
            *(float2*)(Q + (size_t)row * HH + col) =
                make_float2((acc0 + bb.x) * INV_SCALE, (acc1 + bb.y) * INV_SCALE);
        } else if (matsel == 1) {
            float2 bb = *(const float2*)(bk + col);
            float2 pk = *(const float2*)(posK + (size_t)l * HH + col);
            *(float2*)(K + (size_t)row * HH + col) =
                make_float2(acc0 + bb.x + pk.x, acc1 + bb.y + pk.y);
        } else {
            float2 bb = *(const float2*)(bv + col);
            float2 pv = *(const float2*)(posV + (size_t)l * HH + col);
            *(float2*)(V + (size_t)row * HH + col) =
                make_float2(acc0 + bb.x + pv.x, acc1 + bb.y + pv.y);
        }
        if (it < 3) {   // write-late: vmcnt wait lands here, after the dot
            *(float4*)&Bs[(it + 1) & 1][j * TSP + seg16 * 8]     = w0;
            *(float4*)&Bs[(it + 1) & 1][j * TSP + seg16 * 8 + 4] = w1;
        }
        __syncthreads();
    }
}

// ===== attention v5: 2 barriers, wave-autonomous coalesced dots ============
// Dot phase: 8-lane groups read one row (coalesced 128B), compute all 8 qi
// partials, 3x shfl_xor reduce, lane seg writes qi=seg. 257 timeK + <=200 K
// rows in ONE independent loop — no staging, no barriers. PV: thread=(qi,d),
// no atomics, direct att write. LDS 21.5 KB -> ~7 blocks/CU.
__global__ void k_attn(const float* __restrict__ Q, const float* __restrict__ K,
                       const float* __restrict__ V,
                       const float* __restrict__ timeK, const float* __restrict__ timeV,
                       const int* __restrict__ tm,
                       float* __restrict__ att) {
    int bn = blockIdx.x & 31;
    int b = bn >> 2, n = bn & 3;
    int qt = blockIdx.x >> 5;
    int q0 = qt * QT;
    int kmax = q0 + QT - 1;
    int tid = threadIdx.x;

    __shared__ float DTW[QT * NTP];    // 8.4 KB  DT[qi][tau]
    __shared__ float Ssc[QT * SSP];    // 6.7 KB  scores -> P
    __shared__ int   tmst[QT * LL];    // 6.4 KB

    // stage tm rows (coalesced; consumed only after the barrier)
    #pragma unroll
    for (int qi = 0; qi < QT; qi++)
        if (tid < LL)
            tmst[qi * LL + tid] = tm[((size_t)(b * LL + q0 + qi)) * LL + tid];

    int g8 = tid >> 3, seg = tid & 7;  // 32 groups x 8 lanes
    float4 qf[QT];                      // q segment (4 floats) per qi
    #pragma unroll
    for (int qi = 0; qi < QT; qi++)
        qf[qi] = *(const float4*)(Q + ((size_t)(b * LL + q0 + qi)) * HH + n * HDIM + seg * 4);

    // unified DT + QK dot loop: rows [0,NT) = timeK taus, [NT, NT+kmax] = K
    const int R = NT + kmax + 1;
    for (int row = g8; row < R; row += 32) {
        const float* src = (row < NT)
            ? timeK + (size_t)row * HH + n * HDIM + seg * 4
            : K + ((size_t)(b * LL + (row - NT))) * HH + n * HDIM + seg * 4;
        float4 v = *(const float4*)src;
        float p[QT];
        #pragma unroll
        for (int qi = 0; qi < QT; qi++)
            p[qi] = v.x * qf[qi].x + v.y * qf[qi].y + v.z * qf[qi].z + v.w * qf[qi].w;
        #pragma unroll
        for (int qi = 0; qi < QT; qi++) {
            p[qi] += __shfl_xor(p[qi], 1);
            p[qi] += __shfl_xor(p[qi], 2);
            p[qi] += __shfl_xor(p[qi], 4);
        }
        float out = p[0];               // static-index select: lane seg takes qi=seg
        #pragma unroll
        for (int qi = 1; qi < QT; qi++) out = (seg == qi) ? p[qi] : out;
        if (row < NT) DTW[seg * NTP + row] = out;
        else          Ssc[seg * SSP + (row - NT)] = out;   // raw QK; DT added in softmax
    }
    __syncthreads();

    // softmax with fused DT gather: sv = QK + DT[tm[k]]
    int wv = tid >> 6, ln = tid & 63;
    for (int rr = 0; rr < 2; rr++) {
        int qi = wv + rr * 4;
        int qq = q0 + qi;
        float sv[4];
        float m = PADV;
        #pragma unroll
        for (int jj = 0; jj < 4; jj++) {
            int k = ln + 64 * jj;
            sv[jj] = (k <= qq) ? (Ssc[qi * SSP + k] + DTW[qi * NTP + tmst[qi * LL + k]]) : PADV;
            m = fmaxf(m, sv[jj]);
        }
        for (int off = 32; off; off >>= 1) m = fmaxf(m, __shfl_xor(m, off));
        float sum = 0.f;
        #pragma unroll
        for (int jj = 0; jj < 4; jj++) {
            int k = ln + 64 * jj;
            sv[jj] = (k <= qq) ? __expf(sv[jj] - m) : 0.f;
            sum += sv[jj];
        }
        for (int off = 32; off; off >>= 1) sum += __shfl_xor(sum, off);
        float inv = 1.f / sum;
        #pragma unroll
        for (int jj = 0; jj < 4; jj++) {
            int k = ln + 64 * jj;
            if (k < SSP) Ssc[qi * SSP + k] = (k <= qq) ? sv[jj] * inv : 0.f;
        }
    }
    __syncthreads();

    // O = P@(Vh + timeVh[tm]); thread (qi,d) owns one output, 4-way ILP split
    int d = tid & 31, qi = tid >> 5;
    int qq = q0 + qi;
    const float* vb  = V + ((size_t)(b * LL)) * HH + n * HDIM + d;
    const float* tvb = timeV + n * HDIM + d;
    const float* pr  = &Ssc[qi * SSP];
    const int*   tr  = &tmst[qi * LL];
    float a0 = 0.f, a1 = 0.f, a2 = 0.f, a3 = 0.f;
    int k = 0;
    for (; k + 3 <= qq; k += 4) {
        a0 += pr[k]     * (vb[(size_t)(k)     * HH] + tvb[(size_t)tr[k]     * HH]);
        a1 += pr[k + 1] * (vb[(size_t)(k + 1) * HH] + tvb[(size_t)tr[k + 1] * HH]);
        a2 += pr[k + 2] * (vb[(size_t)(k + 2) * HH] + tvb[(size_t)tr[k + 2] * HH]);
        a3 += pr[k + 3] * (vb[(size_t)(k + 3) * HH] + tvb[(size_t)tr[k + 3] * HH]);
    }
    for (; k <= qq; k++)
        a0 += pr[k] * (vb[(size_t)k * HH] + tvb[(size_t)tr[k] * HH]);
    att[((size_t)(b * LL + q0 + qi)) * HH + n * HDIM + d] = (a0 + a1) + (a2 + a3);
}

// ===== FF1 v2 (R4-verified): 200 blocks x 4 col-tiles =====================
__global__ void k_ff1(const float* __restrict__ Qin, const float* __restrict__ att,
                      const float* __restrict__ g, const float* __restrict__ bia,
                      const float* __restrict__ W1, const float* __restrict__ b1,
                      float* __restrict__ h1) {
    int mt = blockIdx.x >> 1, jb0 = (blockIdx.x & 1) * 64;
    int row0 = mt * 16;
    int tid = threadIdx.x;
    __shared__ float As[16 * TSP];
    __shared__ float Bs[2][16 * TSP];

    {   // stage A = LN(Qin+att), 16 threads/row — computed ONCE per 4 tiles
        int r = tid >> 4, seg = tid & 15;
        int row = row0 + r;
        float4 vv[2];
        #pragma unroll
        for (int i = 0; i < 2; i++) {
            int k = seg * 8 + i * 4;
            float4 q4 = *(const float4*)(Qin + (size_t)row * HH + k);
            float4 a4 = *(const float4*)(att + (size_t)row * HH + k);
            vv[i] = make_float4(q4.x + a4.x, q4.y + a4.y, q4.z + a4.z, q4.w + a4.w);
        }
        float s = 0.f, s2 = 0.f;
        #pragma unroll
        for (int i = 0; i < 2; i++) {
            s  += vv[i].x + vv[i].y + vv[i].z + vv[i].w;
            s2 += vv[i].x * vv[i].x + vv[i].y * vv[i].y + vv[i].z * vv[i].z + vv[i].w * vv[i].w;
        }
        #pragma unroll
        for (int off = 1; off < 16; off <<= 1) {
            s  += __shfl_xor(s, off);
            s2 += __shfl_xor(s2, off);
        }
        float mean = s * (1.f / HH);
        float var  = s2 * (1.f / HH) - mean * mean;
        float inv  = 1.f / sqrtf(var + 1e-8f);
        #pragma unroll
        for (int i = 0; i < 2; i++) {
            int k = seg * 8 + i * 4;
            float4 g4 = *(const float4*)(g + k);
            float4 b4 = *(const float4*)(bia + k);
            float4 y;
            y.x = (vv[i].x - mean) * inv * g4.x + b4.x;
            y.y = (vv[i].y - mean) * inv * g4.y + b4.y;
            y.z = (vv[i].z - mean) * inv * g4.z + b4.z;
            y.w = (vv[i].w - mean) * inv * g4.w + b4.w;
            *(float4*)&As[r * TSP + k] = y;
        }
    }
    int j = tid >> 4, seg16 = tid & 15;
    float4 w0 = *(const float4*)(W1 + (size_t)(jb0 + j) * HH + seg16 * 8);
    float4 w1 = *(const float4*)(W1 + (size_t)(jb0 + j) * HH + seg16 * 8 + 4);
    *(float4*)&Bs[0][j * TSP + seg16 * 8]     = w0;
    *(float4*)&Bs[0][j * TSP + seg16 * 8 + 4] = w1;
    __syncthreads();

    int m = tid >> 4, jj = tid & 15;
    const float* ar = &As[m * TSP];
    #pragma unroll
    for (int it = 0; it < 4; it++) {
        int jb = jb0 + it * 16;
        if (it < 3) {
            int jbn = jb0 + (it + 1) * 16;
            w0 = *(const float4*)(W1 + (size_t)(jbn + j) * HH + seg16 * 8);
            w1 = *(const float4*)(W1 + (size_t)(jbn + j) * HH + seg16 * 8 + 4);
        }
        float acc = 0.f;
        const float* br = &Bs[it & 1][jj * TSP];
        #pragma unroll 4
        for (int k4 = 0; k4 < 32; k4++) {
            float4 a = *(const float4*)(ar + k4 * 4);
            float4 b = *(const float4*)(br + k4 * 4);
            acc += a.x * b.x + a.y * b.y + a.z * b.z + a.w * b.w;
        }
        int col = jb + jj;
        float t = acc + b1[col];
        h1[(size_t)(row0 + m) * HH + col] = t > 0.f ? t : 0.f;
        if (it < 3) {
            *(float4*)&Bs[(it + 1) & 1][j * TSP + seg16 * 8]     = w0;
            *(float4*)&Bs[(it + 1) & 1][j * TSP + seg16 * 8 + 4] = w1;
        }
        __syncthreads();
    }
}

// ===== FF2 v2 (R4-verified): 200 blocks x 4 col-tiles =====================
__global__ void k_ff2(const float* __restrict__ h1,
                      const float* __restrict__ Qin, const float* __restrict__ att,
                      const float* __restrict__ g, const float* __restrict__ bia,
                      const float* __restrict__ W2, const float* __restrict__ b2,
                      const int* __restrict__ log_seqs,
                      float* __restrict__ out) {
    int mt = blockIdx.x >> 1, jb0 = (blockIdx.x & 1) * 64;
    int row0 = mt * 16;
    int tid = threadIdx.x;
    __shared__ float As[16 * TSP];
    __shared__ float Bs[2][16 * TSP];
    __shared__ float mu[16], rstd[16];

    {   // stage A = h1; residual row stats ONCE per 4 tiles
        int r = tid >> 4, seg = tid & 15;
        int row = row0 + r;
        #pragma unroll
        for (int i = 0; i < 2; i++) {
            int k = seg * 8 + i * 4;
            *(float4*)&As[r * TSP + k] = *(const float4*)(h1 + (size_t)row * HH + k);
        }
        float s = 0.f, s2 = 0.f;
        #pragma unroll
        for (int i = 0; i < 2; i++) {
            int k = seg * 8 + i * 4;
            float4 q4 = *(const float4*)(Qin + (size_t)row * HH + k);
            float4 a4 = *(const float4*)(att + (size_t)row * HH + k);
            float4 v = make_float4(q4.x + a4.x, q4.y + a4.y, q4.z + a4.z, q4.w + a4.w);
            s  += v.x + v.y + v.z + v.w;
            s2 += v.x * v.x + v.y * v.y + v.z * v.z + v.w * v.w;
        }
        #pragma unroll
        for (int off = 1; off < 16; off <<= 1) {
            s  += __shfl_xor(s, off);
            s2 += __shfl_xor(s2, off);
        }
        float mean = s * (1.f / HH);
        float var  = s2 * (1.f / HH) - mean * mean;
        if (seg == 0) { mu[r] = mean; rstd[r] = 1.f / sqrtf(var + 1e-8f); }
    }
    int j = tid >> 4, seg16 = tid & 15;
    float4 w0 = *(const float4*)(W2 + (size_t)(jb0 + j) * HH + seg16 * 8);
    float4 w1 = *(const float4*)(W2 + (size_t)(jb0 + j) * HH + seg16 * 8 + 4);
    *(float4*)&Bs[0][j * TSP + seg16 * 8]     = w0;
    *(float4*)&Bs[0][j * TSP + seg16 * 8 + 4] = w1;
    __syncthreads();

    int m = tid >> 4, jj = tid & 15;
    const float* ar = &As[m * TSP];
    #pragma unroll
    for (int it = 0; it < 4; it++) {
        int jb = jb0 + it * 16;
        if (it < 3) {
            int jbn = jb0 + (it + 1) * 16;
            w0 = *(const float4*)(W2 + (size_t)(jbn + j) * HH + seg16 * 8);
            w1 = *(const float4*)(W2 + (size_t)(jbn + j) * HH + seg16 * 8 + 4);
        }
        float acc = 0.f;
        const float* br = &Bs[it & 1][jj * TSP];
        #pragma unroll 4
        for (int k4 = 0; k4 < 32; k4++) {
            float4 a = *(const float4*)(ar + k4 * 4);
            float4 b = *(const float4*)(br + k4 * 4);
            acc += a.x * b.x + a.y * b.y + a.z * b.z + a.w * b.w;
        }
        int row = row0 + m;
        int col = jb + jj;
        float resid = Qin[(size_t)row * HH + col] + att[(size_t)row * HH + col];
        float y = (resid - mu[m]) * rstd[m] * g[col] + bia[col];
        float o = acc + b2[col] + y;
        if (log_seqs[row] == 0) o = 0.f;
        out[(size_t)row * HH + col] = o;
        if (it < 3) {
            *(float4*)&Bs[(it + 1) & 1][j * TSP + seg16 * 8]     = w0;
            *(float4*)&Bs[(it + 1) & 1][j * TSP + seg16 * 8 + 4] = w1;
        }
        __syncthreads();
    }
}

// ===== fused last-LN + pos/neg logits: one block per row ==================
__global__ void k_lnlogits(const float* __restrict__ seqs,
                           const float* __restrict__ g, const float* __restrict__ bia,
                           const float* __restrict__ item_emb,
                           const int* __restrict__ pos, const int* __restrict__ neg,
                           float* __restrict__ out) {
    int row = blockIdx.x;
    int h = threadIdx.x;
    float v = seqs[(size_t)row * HH + h];
    float s = v, s2 = v * v;
    for (int off = 32; off; off >>= 1) {
        s  += __shfl_xor(s, off);
        s2 += __shfl_xor(s2, off);
    }
    __shared__ float r1[2], r2[2];
    if ((h & 63) == 0) { r1[h >> 6] = s; r2[h >> 6] = s2; }
    __syncthreads();
    float mean = (r1[0] + r1[1]) * (1.f / HH);
    float var  = (r2[0] + r2[1]) * (1.f / HH) - mean * mean;
    float inv = 1.f / sqrtf(var + 1e-8f);
    float f = (v - mean) * inv * g[h] + bia[h];

    int ip = pos[row], in_ = neg[row];
    float vp = f * item_emb[(size_t)ip * HH + h];
    float vn = f * item_emb[(size_t)in_ * HH + h];
    for (int off = 32; off; off >>= 1) {
        vp += __shfl_xor(vp, off);
        vn += __shfl_xor(vn, off);
    }
    __shared__ float rp[2], rn[2];
    if ((h & 63) == 0) { rp[h >> 6] = vp; rn[h >> 6] = vn; }
    __syncthreads();
    if (h == 0) {
        out[row]      = rp[0] + rp[1];
        out[BL + row] = rn[0] + rn[1];
    }
}

extern "C" void kernel_launch(void* const* d_in, const int* in_sizes, int n_in,
                              void* d_out, int out_size, void* d_ws, size_t ws_size,
                              hipStream_t stream) {
    const int* log_seqs   = (const int*)d_in[1];
    const int* tm         = (const int*)d_in[2];
    const int* pos_seqs   = (const int*)d_in[3];
    const int* neg_seqs   = (const int*)d_in[4];
    const float* item_emb = (const float*)d_in[5];
    const float* posK     = (const float*)d_in[6];
    const float* posV     = (const float*)d_in[7];
    const float* timeK    = (const float*)d_in[8];
    const float* timeV    = (const float*)d_in[9];
    const float* attn_g   = (const float*)d_in[10];
    const float* attn_b   = (const float*)d_in[11];
    const float* Wq       = (const float*)d_in[12];
    const float* bq       = (const float*)d_in[13];
    const float* Wk       = (const float*)d_in[14];
    const float* bk       = (const float*)d_in[15];
    const float* Wv       = (const float*)d_in[16];
    const float* bv       = (const float*)d_in[17];
    const float* fwd_g    = (const float*)d_in[18];
    const float* fwd_b    = (const float*)d_in[19];
    const float* W1       = (const float*)d_in[20];
    const float* b1       = (const float*)d_in[21];
    const float* W2       = (const float*)d_in[22];
    const float* b2       = (const float*)d_in[23];
    const float* last_g   = (const float*)d_in[24];
    const float* last_b   = (const float*)d_in[25];

    float* seqs = (float*)d_ws;            // 7 x B*L*H f32 = ~5.7 MB
    float* Qin  = seqs + (size_t)BL * HH;
    float* Qb   = Qin  + (size_t)BL * HH;
    float* Kb   = Qb   + (size_t)BL * HH;
    float* Vb   = Kb   + (size_t)BL * HH;
    float* att  = Vb   + (size_t)BL * HH;
    float* h1   = att  + (size_t)BL * HH;

    for (int i = 0; i < NBLK; i++) {
        k_qkv_gemm<<<300, 256, 0, stream>>>(i == 0 ? nullptr : seqs, log_seqs, item_emb,
                                            attn_g + i * HH, attn_b + i * HH,
                                            Wq + (size_t)i * HH * HH, bq + i * HH,
                                            Wk + (size_t)i * HH * HH, bk + i * HH,
                                            Wv + (size_t)i * HH * HH, bv + i * HH,
                                            posK, posV, Qin, Qb, Kb, Vb);
        k_attn<<<NQT * 32, 256, 0, stream>>>(Qb, Kb, Vb, timeK, timeV, tm, att);
        k_ff1<<<200, 256, 0, stream>>>(Qin, att, fwd_g + i * HH, fwd_b + i * HH,
                                       W1 + (size_t)i * HH * HH, b1 + i * HH, h1);
        k_ff2<<<200, 256, 0, stream>>>(h1, Qin, att, fwd_g + i * HH, fwd_b + i * HH,
                                       W2 + (size_t)i * HH * HH, b2 + i * HH,
                                       log_seqs, seqs);
    }
    k_lnlogits<<<BL, HH, 0, stream>>>(seqs, last_g, last_b, item_emb,
                                      pos_seqs, neg_seqs, (float*)d_out);
}